// Round 22
// baseline (51.892 us; speedup 1.0000x reference)
//
#include <hip/hip_runtime.h>
#include <hip/hip_bf16.h>
#include <cstdint>
#include <cmath>

#define B_ 512
#define T_ 256
#define C_ 256
#define HS_ 64

typedef short bf16x8 __attribute__((ext_vector_type(8)));
typedef float f32x4 __attribute__((ext_vector_type(4)));

static __device__ __forceinline__ unsigned short f2bf(float f) {
    union { float f; unsigned int u; } v; v.f = f;
    unsigned int r = v.u + 0x7fffu + ((v.u >> 16) & 1u);
    return (unsigned short)(r >> 16);
}

static __device__ __forceinline__ uint2 pack4(f32x4 a) {
    uint2 r;
    r.x = (unsigned)f2bf(a[0]) | ((unsigned)f2bf(a[1]) << 16);
    r.y = (unsigned)f2bf(a[2]) | ((unsigned)f2bf(a[3]) << 16);
    return r;
}

// Vt swizzle key: 4 lg-row-groups (vr stride 4) -> distinct 16B slots {0,4,2,6} (+8: +2)
#define VKEY(vr) ((((vr) & 7) << 4) + (((vr) & 8) << 2))

// Build MFMA B-fragment for W-column f, K-chunk kap:
// frag[j] = W[kap*32 + lg*8 + j][f*16 + ln]  -- 4x64B segments per wave-load, L2-hot.
static __device__ __forceinline__ bf16x8 mkfrag(const float* __restrict__ W,
                                                int f, int kap, int ln, int lg) {
    bf16x8 r;
#pragma unroll
    for (int j = 0; j < 8; ++j)
        r[j] = (short)f2bf(W[(kap * 32 + lg * 8 + j) * HS_ + f * 16 + ln]);
    return r;
}

// ---- Fused kernel: one block per batch. 512 threads / 8 waves. 80 KB LDS -> 2 blocks/CU.
// LDS: K[256][64] @0 (32K), Vt[64][256] @32K (32K), xbuf @64K (16K; Q-transit & P tiles).
// Phase 1: 8 slabs of 32 tokens; wave w: {K/V fid 4+w (both tiles), Q fid w&3 tile w>>2}.
// bkv AND bq W-columns built in-prologue from Wq/Wk/Wv, held in REGISTERS.
// Phase 2: swapped-QK^T (lane = q-row), KVBLK=32, two passes (g = w, 15-w), exp2-domain
// softmax, setprio on MFMA clusters. amdgpu_num_vgpr(128) forces the 4-waves/EU budget
// (occupancy hints leave the allocator at 64 VGPR + spills).
__global__ __launch_bounds__(512)
__attribute__((amdgpu_num_vgpr(128)))
void fused_kernel(const float* __restrict__ x, const float* __restrict__ Wq,
                  const float* __restrict__ Wk, const float* __restrict__ Wv,
                  float* __restrict__ out) {
    __shared__ __align__(16) char smem[81920];
    unsigned short* Ks  = (unsigned short*)(smem);
    unsigned short* Vts = (unsigned short*)(smem + 32768);
    char* xbuf = smem + 65536;

    const int tid = threadIdx.x;
    const int w = tid >> 6, l = tid & 63, ln = l & 15, lg = l >> 4;
    const int b = blockIdx.x;
    const float* xb = x + (size_t)b * (T_ * C_);
    const int qt = w >> 2, qf = w & 3;     // this wave's Q unit: tile qt, fid qf
    const float scale2 = 0.09016844f;      // C^-0.5 * log2(e): softmax in exp2 domain

    float4 st[4];

#define LOADX(S) do { \
    _Pragma("unroll") \
    for (int i_ = 0; i_ < 4; ++i_) \
        st[i_] = *(const float4*)(xb + (S) * 8192 + (size_t)(i_ * 512 + tid) * 4); \
} while (0)

#define DS_WRITE_SLAB() do { \
    _Pragma("unroll") \
    for (int i_ = 0; i_ < 4; ++i_) { \
        const int fidx_ = i_ * 512 + tid, row_ = fidx_ >> 6, c4_ = (fidx_ & 63) * 4; \
        ushort4 hh_; \
        hh_.x = f2bf(st[i_].x); hh_.y = f2bf(st[i_].y); \
        hh_.z = f2bf(st[i_].z); hh_.w = f2bf(st[i_].w); \
        *(ushort4*)(xbuf + row_ * 512 + ((c4_ * 2) ^ ((row_ & 7) << 4))) = hh_; \
    } \
} while (0)

    LOADX(0);                               // slab-0 HBM loads first (long latency)

    // this wave's W-columns, built from global W (L2-hot), held in registers.
    const float* Wkv = (w < 4) ? Wk : Wv;
    const int fkv = w & 3;
    bf16x8 bkv[8], bq[8];
#pragma unroll
    for (int kap = 0; kap < 8; ++kap) {
        bkv[kap] = mkfrag(Wkv, fkv, kap, ln, lg);
        bq[kap]  = mkfrag(Wq, qf, kap, ln, lg);
    }

    uint2 hqQ[8];

#pragma unroll
    for (int s = 0; s < 8; ++s) {
        DS_WRITE_SLAB();
        __syncthreads();
        if (s < 7) LOADX(s + 1);           // next slab lands under this slab's compute

        f32x4 aq   = (f32x4){0.f, 0.f, 0.f, 0.f};
        f32x4 akv0 = (f32x4){0.f, 0.f, 0.f, 0.f};
        f32x4 akv1 = (f32x4){0.f, 0.f, 0.f, 0.f};
#pragma unroll
        for (int kap = 0; kap < 8; ++kap) {
            bf16x8 a0 = *(const bf16x8*)(xbuf + ln * 512
                          + ((kap * 64 + lg * 16) ^ ((ln & 7) << 4)));
            const int R1 = 16 + ln;
            bf16x8 a1 = *(const bf16x8*)(xbuf + R1 * 512
                          + ((kap * 64 + lg * 16) ^ ((R1 & 7) << 4)));
            akv0 = __builtin_amdgcn_mfma_f32_16x16x32_bf16(bkv[kap], a0, akv0, 0, 0, 0);
            akv1 = __builtin_amdgcn_mfma_f32_16x16x32_bf16(bkv[kap], a1, akv1, 0, 0, 0);
            aq   = __builtin_amdgcn_mfma_f32_16x16x32_bf16(bq[kap], qt ? a1 : a0, aq, 0, 0, 0);
        }
        hqQ[s] = pack4(aq);

        if (w < 4) {               // K fid w
#pragma unroll
            for (int tt = 0; tt < 2; ++tt) {
                const int token = s * 32 + tt * 16 + ln;
                uint2 hv = pack4(tt ? akv1 : akv0);
                *(uint2*)((char*)Ks + token * 128
                          + ((w * 32 + lg * 8) ^ ((token & 7) << 4))) = hv;
            }
        } else {                   // V fid w-4, transposed (VKEY swizzle)
#pragma unroll
            for (int tt = 0; tt < 2; ++tt) {
                const int token = s * 32 + tt * 16 + ln;
                f32x4 av = tt ? akv1 : akv0;
#pragma unroll
                for (int i = 0; i < 4; ++i) {
                    const int vr = (w - 4) * 16 + lg * 4 + i;
                    *(unsigned short*)((char*)Vts + vr * 512
                          + ((token * 2) ^ VKEY(vr))) = f2bf(av[i]);
                }
            }
        }
        __syncthreads();           // xbuf reads done before next slab's writes
    }

    // ---- Q transit through xbuf: round A (rows 0-127), round B (rows 128-255) ----
    bf16x8 qa0[2], qa1[2];
#pragma unroll
    for (int s = 0; s < 4; ++s) {
        const int row = s * 32 + qt * 16 + ln;
        *(uint2*)(xbuf + row * 128 + ((qf * 32 + lg * 8) ^ ((row & 7) << 4))) = hqQ[s];
    }
    __syncthreads();
#pragma unroll
    for (int kk = 0; kk < 2; ++kk) {
        const int row = w * 16 + ln;
        qa0[kk] = *(const bf16x8*)(xbuf + row * 128
                    + ((kk * 64 + lg * 16) ^ ((row & 7) << 4)));
    }
    __syncthreads();
#pragma unroll
    for (int s = 4; s < 8; ++s) {
        const int row = (s - 4) * 32 + qt * 16 + ln;
        *(uint2*)(xbuf + row * 128 + ((qf * 32 + lg * 8) ^ ((row & 7) << 4))) = hqQ[s];
    }
    __syncthreads();
#pragma unroll
    for (int kk = 0; kk < 2; ++kk) {
        const int row = (7 - w) * 16 + ln;
        qa1[kk] = *(const bf16x8*)(xbuf + row * 128
                    + ((kk * 64 + lg * 16) ^ ((row & 7) << 4)));
    }
    __syncthreads();

    // ---- phase 2: causal attention, swapped-QK^T (lane = q-row), two passes ----
    unsigned short* Pl = (unsigned short*)(xbuf + w * 1280);   // [16][40] per wave
    float* outb = out + (size_t)b * (T_ * HS_);

#pragma unroll
    for (int pass = 0; pass < 2; ++pass) {
        const int g = pass ? (15 - w) : w;
        const int r0 = g * 16;
        const int qrow = r0 + ln;

        float m = -INFINITY, lsum = 0.f;
        f32x4 o[4];
#pragma unroll
        for (int f = 0; f < 4; ++f) o[f] = (f32x4){0.f, 0.f, 0.f, 0.f};

        const int nkt = (g >> 1) + 1;
        for (int kt = 0; kt < nkt; ++kt) {
            const int n0 = kt * 32;

            f32x4 s2[2];
            __builtin_amdgcn_s_setprio(1);
#pragma unroll
            for (int h = 0; h < 2; ++h) {
                const int key = n0 + 16 * h + ln;
                bf16x8 kb0 = *(const bf16x8*)((char*)Ks + key * 128
                               + ((lg * 16) ^ ((key & 7) << 4)));
                bf16x8 kb1 = *(const bf16x8*)((char*)Ks + key * 128
                               + ((64 + lg * 16) ^ ((key & 7) << 4)));
                f32x4 z = (f32x4){0.f, 0.f, 0.f, 0.f};
                z = __builtin_amdgcn_mfma_f32_16x16x32_bf16(kb0, pass ? qa1[0] : qa0[0], z, 0, 0, 0);
                s2[h] = __builtin_amdgcn_mfma_f32_16x16x32_bf16(kb1, pass ? qa1[1] : qa0[1], z, 0, 0, 0);
            }
            __builtin_amdgcn_s_setprio(0);

            // mask + scale into exp2 domain
            float sm[2][4];
#pragma unroll
            for (int h = 0; h < 2; ++h)
#pragma unroll
                for (int r = 0; r < 4; ++r) {
                    const int key = n0 + 16 * h + lg * 4 + r;
                    float v = s2[h][r] * scale2;
                    sm[h][r] = (qrow >= key) ? v : -INFINITY;
                }

            float tmax = fmaxf(fmaxf(fmaxf(sm[0][0], sm[0][1]), fmaxf(sm[0][2], sm[0][3])),
                               fmaxf(fmaxf(sm[1][0], sm[1][1]), fmaxf(sm[1][2], sm[1][3])));
            tmax = fmaxf(tmax, __shfl_xor(tmax, 16, 64));
            tmax = fmaxf(tmax, __shfl_xor(tmax, 32, 64));

            // T13 defer-max (log2 units)
            if (!__all(tmax <= m)) {
                const float mn = fmaxf(m, tmax);
                const float fac = exp2f(m - mn);
                lsum *= fac;
                m = mn;
#pragma unroll
                for (int f = 0; f < 4; ++f) o[f] *= fac;
            }

            float p[2][4];
            float rs = 0.f;
#pragma unroll
            for (int h = 0; h < 2; ++h)
#pragma unroll
                for (int r = 0; r < 4; ++r) {
                    p[h][r] = exp2f(sm[h][r] - m);
                    rs += p[h][r];
                }
            rs += __shfl_xor(rs, 16, 64);
            rs += __shfl_xor(rs, 32, 64);
            lsum += rs;

            // P -> LDS: row = q-row(ln), col = key (packed bf16 pairs)
#pragma unroll
            for (int h = 0; h < 2; ++h)
#pragma unroll
                for (int rp = 0; rp < 2; ++rp) {
                    unsigned pk = (unsigned)f2bf(p[h][2 * rp])
                                | ((unsigned)f2bf(p[h][2 * rp + 1]) << 16);
                    *(unsigned*)(Pl + ln * 40 + 16 * h + lg * 4 + 2 * rp) = pk;
                }

            bf16x8 pa = *(const bf16x8*)(Pl + ln * 40 + lg * 8);

            // PV: A = V^T (rows = features), B = P (cols = q-rows)
            __builtin_amdgcn_s_setprio(1);
#pragma unroll
            for (int f = 0; f < 4; ++f) {
                const int vr = f * 16 + ln;
                bf16x8 vb = *(const bf16x8*)((char*)Vts + vr * 512
                              + ((n0 * 2 + lg * 16) ^ VKEY(vr)));
                o[f] = __builtin_amdgcn_mfma_f32_16x16x32_bf16(vb, pa, o[f], 0, 0, 0);
            }
            __builtin_amdgcn_s_setprio(0);
        }

        // epilogue: lane owns row qrow, cols f*16 + lg*4 .. +3 -> float4
        const float inv = 1.f / lsum;
#pragma unroll
        for (int f = 0; f < 4; ++f) {
            float4 sv;
            sv.x = o[f][0] * inv; sv.y = o[f][1] * inv;
            sv.z = o[f][2] * inv; sv.w = o[f][3] * inv;
            *(float4*)(outb + (size_t)qrow * HS_ + f * 16 + lg * 4) = sv;
        }
    }
}

extern "C" void kernel_launch(void* const* d_in, const int* in_sizes, int n_in,
                              void* d_out, int out_size, void* d_ws, size_t ws_size,
                              hipStream_t stream) {
    const float* x  = (const float*)d_in[0];
    const float* Wq = (const float*)d_in[1];
    const float* Wk = (const float*)d_in[2];
    const float* Wv = (const float*)d_in[3];
    float* out = (float*)d_out;

    fused_kernel<<<B_, 512, 0, stream>>>(x, Wq, Wk, Wv, out);
}

// Round 23
// 49.484 us; speedup vs baseline: 1.0487x; 1.0487x over previous
//
#include <hip/hip_runtime.h>
#include <hip/hip_bf16.h>
#include <cstdint>
#include <cmath>

#define B_ 512
#define T_ 256
#define C_ 256
#define HS_ 64

typedef short bf16x8 __attribute__((ext_vector_type(8)));
typedef float f32x4 __attribute__((ext_vector_type(4)));

static __device__ __forceinline__ unsigned short f2bf(float f) {
    union { float f; unsigned int u; } v; v.f = f;
    unsigned int r = v.u + 0x7fffu + ((v.u >> 16) & 1u);
    return (unsigned short)(r >> 16);
}

static __device__ __forceinline__ uint2 pack4(f32x4 a) {
    uint2 r;
    r.x = (unsigned)f2bf(a[0]) | ((unsigned)f2bf(a[1]) << 16);
    r.y = (unsigned)f2bf(a[2]) | ((unsigned)f2bf(a[3]) << 16);
    return r;
}

// Vt swizzle key: 4 lg-row-groups (vr stride 4) -> distinct 16B slots {0,4,2,6} (+8: +2)
#define VKEY(vr) ((((vr) & 7) << 4) + (((vr) & 8) << 2))

// Build MFMA B-fragment for W-column f, K-chunk kap:
// frag[j] = W[kap*32 + lg*8 + j][f*16 + ln]  -- 4x64B segments per wave-load, L2-hot.
static __device__ __forceinline__ bf16x8 mkfrag(const float* __restrict__ W,
                                                int f, int kap, int ln, int lg) {
    bf16x8 r;
#pragma unroll
    for (int j = 0; j < 8; ++j)
        r[j] = (short)f2bf(W[(kap * 32 + lg * 8 + j) * HS_ + f * 16 + ln]);
    return r;
}

// ---- Fused kernel: one block per batch. 512 threads / 8 waves. 80 KB LDS -> 2 blocks/CU.
// LDS: K[256][64] @0 (32K), Vt[64][256] @32K (32K), xbuf @64K (16K; Q-transit & P tiles).
// Phase 1: 8 slabs of 32 tokens; wave w: {K/V fid 4+w (both tiles), Q fid w&3 tile w>>2}.
// bkv AND bq W-columns built in-prologue from Wq/Wk/Wv (no wt_kernel pre-pass) and
// held in REGISTERS. Phase 2: swapped-QK^T, KVBLK=32, two passes (g = w, 15-w),
// setprio on MFMA clusters. amdgpu_num_vgpr(128) forces the 4-waves/EU budget
// (occupancy hints leave the allocator at 64 VGPR + spills).
__global__ __launch_bounds__(512)
__attribute__((amdgpu_num_vgpr(128)))
void fused_kernel(const float* __restrict__ x, const float* __restrict__ Wq,
                  const float* __restrict__ Wk, const float* __restrict__ Wv,
                  float* __restrict__ out) {
    __shared__ __align__(16) char smem[81920];
    unsigned short* Ks  = (unsigned short*)(smem);
    unsigned short* Vts = (unsigned short*)(smem + 32768);
    char* xbuf = smem + 65536;

    const int tid = threadIdx.x;
    const int w = tid >> 6, l = tid & 63, ln = l & 15, lg = l >> 4;
    const int b = blockIdx.x;
    const float* xb = x + (size_t)b * (T_ * C_);
    const int qt = w >> 2, qf = w & 3;     // this wave's Q unit: tile qt, fid qf
    const float scale = 0.0625f;           // C^-0.5

    float4 st[4];

#define LOADX(S) do { \
    _Pragma("unroll") \
    for (int i_ = 0; i_ < 4; ++i_) \
        st[i_] = *(const float4*)(xb + (S) * 8192 + (size_t)(i_ * 512 + tid) * 4); \
} while (0)

#define DS_WRITE_SLAB() do { \
    _Pragma("unroll") \
    for (int i_ = 0; i_ < 4; ++i_) { \
        const int fidx_ = i_ * 512 + tid, row_ = fidx_ >> 6, c4_ = (fidx_ & 63) * 4; \
        ushort4 hh_; \
        hh_.x = f2bf(st[i_].x); hh_.y = f2bf(st[i_].y); \
        hh_.z = f2bf(st[i_].z); hh_.w = f2bf(st[i_].w); \
        *(ushort4*)(xbuf + row_ * 512 + ((c4_ * 2) ^ ((row_ & 7) << 4))) = hh_; \
    } \
} while (0)

    LOADX(0);                               // slab-0 HBM loads first (long latency)

    // this wave's W-columns, built from global W (L2-hot), held in registers.
    // fid 4+w: w<4 -> Wk col w ; w>=4 -> Wv col w-4. bq: Wq col qf.
    const float* Wkv = (w < 4) ? Wk : Wv;
    const int fkv = w & 3;
    bf16x8 bkv[8], bq[8];
#pragma unroll
    for (int kap = 0; kap < 8; ++kap) {
        bkv[kap] = mkfrag(Wkv, fkv, kap, ln, lg);
        bq[kap]  = mkfrag(Wq, qf, kap, ln, lg);
    }

    uint2 hqQ[8];

#pragma unroll
    for (int s = 0; s < 8; ++s) {
        DS_WRITE_SLAB();
        __syncthreads();
        if (s < 7) LOADX(s + 1);           // next slab lands under this slab's compute

        f32x4 aq   = (f32x4){0.f, 0.f, 0.f, 0.f};
        f32x4 akv0 = (f32x4){0.f, 0.f, 0.f, 0.f};
        f32x4 akv1 = (f32x4){0.f, 0.f, 0.f, 0.f};
#pragma unroll
        for (int kap = 0; kap < 8; ++kap) {
            bf16x8 a0 = *(const bf16x8*)(xbuf + ln * 512
                          + ((kap * 64 + lg * 16) ^ ((ln & 7) << 4)));
            const int R1 = 16 + ln;
            bf16x8 a1 = *(const bf16x8*)(xbuf + R1 * 512
                          + ((kap * 64 + lg * 16) ^ ((R1 & 7) << 4)));
            akv0 = __builtin_amdgcn_mfma_f32_16x16x32_bf16(bkv[kap], a0, akv0, 0, 0, 0);
            akv1 = __builtin_amdgcn_mfma_f32_16x16x32_bf16(bkv[kap], a1, akv1, 0, 0, 0);
            aq   = __builtin_amdgcn_mfma_f32_16x16x32_bf16(bq[kap], qt ? a1 : a0, aq, 0, 0, 0);
        }
        hqQ[s] = pack4(aq);

        if (w < 4) {               // K fid w
#pragma unroll
            for (int tt = 0; tt < 2; ++tt) {
                const int token = s * 32 + tt * 16 + ln;
                uint2 hv = pack4(tt ? akv1 : akv0);
                *(uint2*)((char*)Ks + token * 128
                          + ((w * 32 + lg * 8) ^ ((token & 7) << 4))) = hv;
            }
        } else {                   // V fid w-4, transposed (VKEY swizzle)
#pragma unroll
            for (int tt = 0; tt < 2; ++tt) {
                const int token = s * 32 + tt * 16 + ln;
                f32x4 av = tt ? akv1 : akv0;
#pragma unroll
                for (int i = 0; i < 4; ++i) {
                    const int vr = (w - 4) * 16 + lg * 4 + i;
                    *(unsigned short*)((char*)Vts + vr * 512
                          + ((token * 2) ^ VKEY(vr))) = f2bf(av[i]);
                }
            }
        }
        __syncthreads();           // xbuf reads done before next slab's writes
    }

    // ---- Q transit through xbuf: round A (rows 0-127), round B (rows 128-255) ----
    bf16x8 qa0[2], qa1[2];
#pragma unroll
    for (int s = 0; s < 4; ++s) {
        const int row = s * 32 + qt * 16 + ln;
        *(uint2*)(xbuf + row * 128 + ((qf * 32 + lg * 8) ^ ((row & 7) << 4))) = hqQ[s];
    }
    __syncthreads();
#pragma unroll
    for (int kk = 0; kk < 2; ++kk) {
        const int row = w * 16 + ln;
        qa0[kk] = *(const bf16x8*)(xbuf + row * 128
                    + ((kk * 64 + lg * 16) ^ ((row & 7) << 4)));
    }
    __syncthreads();
#pragma unroll
    for (int s = 4; s < 8; ++s) {
        const int row = (s - 4) * 32 + qt * 16 + ln;
        *(uint2*)(xbuf + row * 128 + ((qf * 32 + lg * 8) ^ ((row & 7) << 4))) = hqQ[s];
    }
    __syncthreads();
#pragma unroll
    for (int kk = 0; kk < 2; ++kk) {
        const int row = (7 - w) * 16 + ln;
        qa1[kk] = *(const bf16x8*)(xbuf + row * 128
                    + ((kk * 64 + lg * 16) ^ ((row & 7) << 4)));
    }
    __syncthreads();

    // ---- phase 2: causal attention, swapped-QK^T (lane = q-row), two passes ----
    unsigned short* Pl = (unsigned short*)(xbuf + w * 1280);   // [16][40] per wave
    float* outb = out + (size_t)b * (T_ * HS_);

#pragma unroll
    for (int pass = 0; pass < 2; ++pass) {
        const int g = pass ? (15 - w) : w;
        const int r0 = g * 16;
        const int qrow = r0 + ln;

        float m = -INFINITY, lsum = 0.f;
        f32x4 o[4];
#pragma unroll
        for (int f = 0; f < 4; ++f) o[f] = (f32x4){0.f, 0.f, 0.f, 0.f};

        const int nkt = (g >> 1) + 1;
        for (int kt = 0; kt < nkt; ++kt) {
            const int n0 = kt * 32;

            f32x4 s2[2];
            __builtin_amdgcn_s_setprio(1);
#pragma unroll
            for (int h = 0; h < 2; ++h) {
                const int key = n0 + 16 * h + ln;
                bf16x8 kb0 = *(const bf16x8*)((char*)Ks + key * 128
                               + ((lg * 16) ^ ((key & 7) << 4)));
                bf16x8 kb1 = *(const bf16x8*)((char*)Ks + key * 128
                               + ((64 + lg * 16) ^ ((key & 7) << 4)));
                f32x4 z = (f32x4){0.f, 0.f, 0.f, 0.f};
                z = __builtin_amdgcn_mfma_f32_16x16x32_bf16(kb0, pass ? qa1[0] : qa0[0], z, 0, 0, 0);
                s2[h] = __builtin_amdgcn_mfma_f32_16x16x32_bf16(kb1, pass ? qa1[1] : qa0[1], z, 0, 0, 0);
            }
            __builtin_amdgcn_s_setprio(0);

            float sm[2][4];
#pragma unroll
            for (int h = 0; h < 2; ++h)
#pragma unroll
                for (int r = 0; r < 4; ++r) {
                    const int key = n0 + 16 * h + lg * 4 + r;
                    float v = s2[h][r] * scale;
                    sm[h][r] = (qrow >= key) ? v : -INFINITY;
                }

            float tmax = fmaxf(fmaxf(fmaxf(sm[0][0], sm[0][1]), fmaxf(sm[0][2], sm[0][3])),
                               fmaxf(fmaxf(sm[1][0], sm[1][1]), fmaxf(sm[1][2], sm[1][3])));
            tmax = fmaxf(tmax, __shfl_xor(tmax, 16, 64));
            tmax = fmaxf(tmax, __shfl_xor(tmax, 32, 64));

            // T13 defer-max
            if (!__all(tmax <= m)) {
                const float mn = fmaxf(m, tmax);
                const float fac = __expf(m - mn);
                lsum *= fac;
                m = mn;
#pragma unroll
                for (int f = 0; f < 4; ++f) o[f] *= fac;
            }

            float p[2][4];
            float rs = 0.f;
#pragma unroll
            for (int h = 0; h < 2; ++h)
#pragma unroll
                for (int r = 0; r < 4; ++r) {
                    p[h][r] = __expf(sm[h][r] - m);
                    rs += p[h][r];
                }
            rs += __shfl_xor(rs, 16, 64);
            rs += __shfl_xor(rs, 32, 64);
            lsum += rs;

            // P -> LDS: row = q-row(ln), col = key (packed bf16 pairs)
#pragma unroll
            for (int h = 0; h < 2; ++h)
#pragma unroll
                for (int rp = 0; rp < 2; ++rp) {
                    unsigned pk = (unsigned)f2bf(p[h][2 * rp])
                                | ((unsigned)f2bf(p[h][2 * rp + 1]) << 16);
                    *(unsigned*)(Pl + ln * 40 + 16 * h + lg * 4 + 2 * rp) = pk;
                }

            bf16x8 pa = *(const bf16x8*)(Pl + ln * 40 + lg * 8);

            // PV: A = V^T (rows = features), B = P (cols = q-rows)
            __builtin_amdgcn_s_setprio(1);
#pragma unroll
            for (int f = 0; f < 4; ++f) {
                const int vr = f * 16 + ln;
                bf16x8 vb = *(const bf16x8*)((char*)Vts + vr * 512
                              + ((n0 * 2 + lg * 16) ^ VKEY(vr)));
                o[f] = __builtin_amdgcn_mfma_f32_16x16x32_bf16(vb, pa, o[f], 0, 0, 0);
            }
            __builtin_amdgcn_s_setprio(0);
        }

        // epilogue: lane owns row qrow, cols f*16 + lg*4 .. +3 -> float4
        const float inv = 1.f / lsum;
#pragma unroll
        for (int f = 0; f < 4; ++f) {
            float4 sv;
            sv.x = o[f][0] * inv; sv.y = o[f][1] * inv;
            sv.z = o[f][2] * inv; sv.w = o[f][3] * inv;
            *(float4*)(outb + (size_t)qrow * HS_ + f * 16 + lg * 4) = sv;
        }
    }
}

extern "C" void kernel_launch(void* const* d_in, const int* in_sizes, int n_in,
                              void* d_out, int out_size, void* d_ws, size_t ws_size,
                              hipStream_t stream) {
    const float* x  = (const float*)d_in[0];
    const float* Wq = (const float*)d_in[1];
    const float* Wk = (const float*)d_in[2];
    const float* Wv = (const float*)d_in[3];
    float* out = (float*)d_out;

    fused_kernel<<<B_, 512, 0, stream>>>(x, Wq, Wk, Wv, out);
}